// Round 2
// baseline (4775.082 us; speedup 1.0000x reference)
//
#include <hip/hip_runtime.h>
#include <math.h>

// ---------------- constants ----------------
#define NIMG   2048   // B*S
#define BATCH  64
#define SEQ    32

__device__ __forceinline__ float siluf(float v) { return v / (1.0f + expf(-v)); }
__device__ __forceinline__ float reluf(float v) { return v > 0.0f ? v : 0.0f; }
__device__ __forceinline__ float softplusf(float x) {
    return x > 0.0f ? x + log1pf(expf(-x)) : log1pf(expf(x));
}

// ---------------- conv1: (2048,4,84,84)/255 -> (2048,32,20,20), k=8 s=4, relu ----
// grid (2048,4): image x 5-output-row chunk. block 192 (160 compute).
// thread tile 4oc x 5ox; shared xr[24] covers all 5 outputs (LDS-balanced).
__global__ __launch_bounds__(192, 3) void k_conv1(const float* __restrict__ x,
                                                  const float* __restrict__ w,
                                                  const float* __restrict__ bias,
                                                  float* __restrict__ out) {
    __shared__ float s_in[4][24][84];   // 32.25 KB -> 5 blocks/CU
    const int tid = threadIdx.x;
    const int img = blockIdx.x;
    const int chunk = blockIdx.y;           // 5 output rows per chunk
    const float* __restrict__ xin = x + (size_t)img * (4 * 84 * 84);
    const int row0 = chunk * 20;            // first input row of chunk

    // load 24 input rows x 84 cols x 4 ic  (2016 float4)
    for (int i = tid; i < 2016; i += 192) {
        int ic = i / 504, rem = i % 504;
        int r = rem / 21, c4 = rem % 21;
        float4 v = *(const float4*)&xin[(size_t)(ic * 84 + row0 + r) * 84 + c4 * 4];
        v.x *= (1.0f / 255.0f); v.y *= (1.0f / 255.0f);
        v.z *= (1.0f / 255.0f); v.w *= (1.0f / 255.0f);
        *(float4*)&s_in[ic][r][c4 * 4] = v;
    }
    __syncthreads();

    if (tid < 160) {
        const int ocg = tid / 20;           // 0..7 (4 oc each)
        const int pix = tid % 20;
        const int oy_l = pix / 4;           // 0..4
        const int oxg  = pix % 4;           // 0..3 (5 ox each)
        const int oc0 = ocg * 4;
        const int iy0 = oy_l * 4;
        const int col0 = oxg * 20;

        float acc[4][5];
        #pragma unroll
        for (int o = 0; o < 4; ++o)
            #pragma unroll
            for (int j = 0; j < 5; ++j) acc[o][j] = 0.0f;

        for (int ic = 0; ic < 4; ++ic) {
            #pragma unroll
            for (int ky = 0; ky < 8; ++ky) {
                const float* irow = &s_in[ic][iy0 + ky][col0];
                float xr[24];
                #pragma unroll
                for (int t = 0; t < 6; ++t) {
                    float4 v = *(const float4*)(irow + t * 4);
                    xr[t * 4] = v.x; xr[t * 4 + 1] = v.y; xr[t * 4 + 2] = v.z; xr[t * 4 + 3] = v.w;
                }
                #pragma unroll
                for (int o = 0; o < 4; ++o) {
                    const float* wp = w + ((size_t)(oc0 + o) * 4 + ic) * 64 + ky * 8;
                    float4 wa = *(const float4*)wp;
                    float4 wb = *(const float4*)(wp + 4);
                    #pragma unroll
                    for (int j = 0; j < 5; ++j) {
                        const float* xp = &xr[j * 4];
                        acc[o][j] += wa.x * xp[0] + wa.y * xp[1] + wa.z * xp[2] + wa.w * xp[3]
                                   + wb.x * xp[4] + wb.y * xp[5] + wb.z * xp[6] + wb.w * xp[7];
                    }
                }
            }
        }

        const int oy = chunk * 5 + oy_l;
        #pragma unroll
        for (int o = 0; o < 4; ++o) {
            float bb = bias[oc0 + o];
            #pragma unroll
            for (int j = 0; j < 5; ++j)
                out[((size_t)img * 32 + oc0 + o) * 400 + oy * 20 + oxg * 5 + j] = reluf(acc[o][j] + bb);
        }
    }
}

// ---------------- conv2: (2048,32,20,20) -> (2048,64,9,9), k=4 s=2, relu ----
// grid 2048, block 192 (144 compute). thread tile 4oc x 9ox.
__global__ __launch_bounds__(192, 2) void k_conv2(const float* __restrict__ in,
                                                  const float* __restrict__ w,
                                                  const float* __restrict__ bias,
                                                  float* __restrict__ out) {
    __shared__ float s_in[32][20][20];  // 51.2 KB -> 3 blocks/CU
    const int tid = threadIdx.x;
    const int img = blockIdx.x;
    const float* __restrict__ src = in + (size_t)img * 12800;
    for (int i = tid; i < 3200; i += 192) ((float4*)s_in)[i] = ((const float4*)src)[i];
    __syncthreads();

    if (tid < 144) {
        const int ocg = tid / 9, oy = tid % 9;
        const int oc0 = ocg * 4;
        float acc[4][9];
        #pragma unroll
        for (int o = 0; o < 4; ++o)
            #pragma unroll
            for (int j = 0; j < 9; ++j) acc[o][j] = 0.0f;

        for (int ic = 0; ic < 32; ++ic) {
            #pragma unroll
            for (int ky = 0; ky < 4; ++ky) {
                const float* irow = &s_in[ic][2 * oy + ky][0];
                float xr[20];
                #pragma unroll
                for (int t = 0; t < 5; ++t) {
                    float4 v = *(const float4*)(irow + t * 4);
                    xr[t * 4] = v.x; xr[t * 4 + 1] = v.y; xr[t * 4 + 2] = v.z; xr[t * 4 + 3] = v.w;
                }
                #pragma unroll
                for (int o = 0; o < 4; ++o) {
                    float4 wv = *(const float4*)(w + ((size_t)(oc0 + o) * 32 + ic) * 16 + ky * 4);
                    #pragma unroll
                    for (int ox = 0; ox < 9; ++ox) {
                        acc[o][ox] += wv.x * xr[2 * ox] + wv.y * xr[2 * ox + 1]
                                    + wv.z * xr[2 * ox + 2] + wv.w * xr[2 * ox + 3];
                    }
                }
            }
        }
        #pragma unroll
        for (int o = 0; o < 4; ++o) {
            float bb = bias[oc0 + o];
            #pragma unroll
            for (int ox = 0; ox < 9; ++ox)
                out[((size_t)img * 64 + oc0 + o) * 81 + oy * 9 + ox] = reluf(acc[o][ox] + bb);
        }
    }
}

// ---------------- conv3: (2048,64,9,9) -> (2048,64,7,7) flat, k=3 s=1, relu ----
// grid 2048, block 128 (112 compute). thread tile 4oc x 7ox. padded LDS rows (12).
__global__ __launch_bounds__(128, 2) void k_conv3(const float* __restrict__ in,
                                                  const float* __restrict__ w,
                                                  const float* __restrict__ bias,
                                                  float* __restrict__ out) {
    __shared__ float s_in[64][9][12];   // 27.6 KB -> 5 blocks/CU
    const int tid = threadIdx.x;
    const int img = blockIdx.x;
    const float* __restrict__ src = in + (size_t)img * 5184;
    for (int i = tid; i < 1296; i += 128) {
        float4 v = ((const float4*)src)[i];
        int base = i * 4;
        #pragma unroll
        for (int e = 0; e < 4; ++e) {
            int idx = base + e;
            int ic = idx / 81, rem = idx % 81;
            float val = (e == 0) ? v.x : (e == 1) ? v.y : (e == 2) ? v.z : v.w;
            s_in[ic][rem / 9][rem % 9] = val;
        }
    }
    __syncthreads();

    if (tid < 112) {
        const int ocg = tid / 7, oy = tid % 7;
        const int oc0 = ocg * 4;
        float acc[4][7];
        #pragma unroll
        for (int o = 0; o < 4; ++o)
            #pragma unroll
            for (int j = 0; j < 7; ++j) acc[o][j] = 0.0f;

        for (int ic = 0; ic < 64; ++ic) {
            #pragma unroll
            for (int ky = 0; ky < 3; ++ky) {
                const float* irow = &s_in[ic][oy + ky][0];
                float xr[12];
                #pragma unroll
                for (int t = 0; t < 3; ++t) {
                    float4 v = *(const float4*)(irow + t * 4);
                    xr[t * 4] = v.x; xr[t * 4 + 1] = v.y; xr[t * 4 + 2] = v.z; xr[t * 4 + 3] = v.w;
                }
                #pragma unroll
                for (int o = 0; o < 4; ++o) {
                    const float* wp = w + ((size_t)(oc0 + o) * 64 + ic) * 9 + ky * 3;
                    float w0 = wp[0], w1 = wp[1], w2 = wp[2];
                    #pragma unroll
                    for (int ox = 0; ox < 7; ++ox)
                        acc[o][ox] += w0 * xr[ox] + w1 * xr[ox + 1] + w2 * xr[ox + 2];
                }
            }
        }
        #pragma unroll
        for (int o = 0; o < 4; ++o) {
            float bb = bias[oc0 + o];
            #pragma unroll
            for (int ox = 0; ox < 7; ++ox)
                out[(size_t)img * 3136 + (oc0 + o) * 49 + oy * 7 + ox] = reluf(acc[o][ox] + bb);
        }
    }
}

// ---------------- generic fp32 GEMM: C[M,N] = A[M,K] @ W[N,K]^T ----
__global__ __launch_bounds__(256) void k_gemm(const float* __restrict__ A,
                                              const float* __restrict__ W,
                                              float* __restrict__ C,
                                              int M, int N, int K, int kpz) {
    __shared__ float As[16][68];
    __shared__ float Ws[16][68];
    const int tid = threadIdx.x;
    const int m0 = blockIdx.x * 64, n0 = blockIdx.y * 64;
    const int k0 = blockIdx.z * kpz;
    const int lr = tid >> 4, lc = tid & 15;
    const int tm = tid >> 4, tn = tid & 15;

    float acc[4][4];
    #pragma unroll
    for (int i = 0; i < 4; ++i)
        #pragma unroll
        for (int j = 0; j < 4; ++j) acc[i][j] = 0.0f;

    for (int kc = 0; kc < kpz; kc += 16) {
        const int kb = k0 + kc + lc;
        __syncthreads();
        #pragma unroll
        for (int i = 0; i < 4; ++i) {
            int r = lr + 16 * i;
            As[lc][r] = A[(size_t)(m0 + r) * K + kb];
            int wr = n0 + r;
            Ws[lc][r] = (wr < N) ? W[(size_t)wr * K + kb] : 0.0f;
        }
        __syncthreads();
        #pragma unroll
        for (int kk = 0; kk < 16; ++kk) {
            float4 a = *(const float4*)&As[kk][tm * 4];
            float4 b = *(const float4*)&Ws[kk][tn * 4];
            acc[0][0] += a.x * b.x; acc[0][1] += a.x * b.y; acc[0][2] += a.x * b.z; acc[0][3] += a.x * b.w;
            acc[1][0] += a.y * b.x; acc[1][1] += a.y * b.y; acc[1][2] += a.y * b.z; acc[1][3] += a.y * b.w;
            acc[2][0] += a.z * b.x; acc[2][1] += a.z * b.y; acc[2][2] += a.z * b.z; acc[2][3] += a.z * b.w;
            acc[3][0] += a.w * b.x; acc[3][1] += a.w * b.y; acc[3][2] += a.w * b.z; acc[3][3] += a.w * b.w;
        }
    }

    float* Cz = C + (size_t)blockIdx.z * M * N;
    #pragma unroll
    for (int i = 0; i < 4; ++i) {
        int m = m0 + tm * 4 + i;
        #pragma unroll
        for (int j = 0; j < 4; ++j) {
            int n = n0 + tn * 4 + j;
            if (n < N) Cz[(size_t)m * N + n] = acc[i][j];
        }
    }
}

// ---------------- reduce 7 K-split partials + bias ----
__global__ __launch_bounds__(256) void k_reduce7(const float* __restrict__ P,
                                                 const float* __restrict__ bias,
                                                 float* __restrict__ out) {
    int idx = blockIdx.x * 256 + threadIdx.x;
    int n = idx & 127;
    float s = bias[n];
    #pragma unroll
    for (int z = 0; z < 7; ++z) s += P[(size_t)z * 2048 * 128 + idx];
    out[idx] = s;
}

// ---------------- depthwise causal conv1d (k=4) + bias + silu ----
__global__ __launch_bounds__(256) void k_conv1d(const float* __restrict__ xz,
                                                const float* __restrict__ w,
                                                const float* __restrict__ bias,
                                                float* __restrict__ u) {
    const int b = blockIdx.x, sg = blockIdx.y;
    const int d = threadIdx.x;
    const float w0 = w[d * 4], w1 = w[d * 4 + 1], w2 = w[d * 4 + 2], w3 = w[d * 4 + 3];
    const float bb = bias[d];
    const int s0 = sg * 8;
    float p1 = 0.0f, p2 = 0.0f, p3 = 0.0f;
    int sstart = (sg == 0) ? 0 : s0 - 3;
    for (int s = sstart; s < s0 + 8; ++s) {
        float cur = xz[(size_t)(b * 32 + s) * 512 + d];
        if (s >= s0) {
            float v = w0 * p3 + w1 * p2 + w2 * p1 + w3 * cur + bb;
            u[(size_t)(b * 32 + s) * 256 + d] = siluf(v);
        }
        p3 = p2; p2 = p1; p1 = cur;
    }
}

// ---------------- dt = softplus(x_dbl[:, :8] @ dt_proj_w^T + dt_proj_b) ----
__global__ __launch_bounds__(256) void k_dtproj(const float* __restrict__ xdbl,
                                                const float* __restrict__ w,
                                                const float* __restrict__ bias,
                                                float* __restrict__ dt) {
    const int row = blockIdx.x;
    const int j = threadIdx.x;
    float r[8];
    #pragma unroll
    for (int k = 0; k < 8; ++k) r[k] = xdbl[(size_t)row * 72 + k];
    float acc = bias[j];
    #pragma unroll
    for (int k = 0; k < 8; ++k) acc += r[k] * w[j * 8 + k];
    dt[(size_t)row * 256 + j] = softplusf(acc);
}

// ---------------- selective scan; only final-timestep output needed ----
__global__ __launch_bounds__(256) void k_scan(const float* __restrict__ xdbl,
                                              const float* __restrict__ dt,
                                              const float* __restrict__ u,
                                              const float* __restrict__ A_log,
                                              const float* __restrict__ Dv,
                                              const float* __restrict__ xz,
                                              float* __restrict__ ylast) {
    const int blk = blockIdx.x;
    const int b = blk >> 5, dg = blk & 31;
    const int lane = threadIdx.x & 63;
    const int wv = threadIdx.x >> 6;
    const int n = lane & 31;
    const int d = dg * 8 + wv * 2 + (lane >> 5);

    const float A = -expf(A_log[d * 32 + n]);
    float h = 0.0f;
    const size_t rowbase = (size_t)b * 32;
    for (int s = 0; s < 32; ++s) {
        size_t r = rowbase + s;
        float dtv = dt[r * 256 + d];
        float Bn  = xdbl[r * 72 + 8 + n];
        float uv  = u[r * 256 + d];
        float dA  = expf(dtv * A);
        h = dA * h + dtv * Bn * uv;
    }
    size_t r31 = rowbase + 31;
    float yv = h * xdbl[r31 * 72 + 40 + n];
    #pragma unroll
    for (int off = 16; off > 0; off >>= 1) yv += __shfl_xor(yv, off);
    if (n == 0) {
        float uv31 = u[r31 * 256 + d];
        float y = yv + Dv[d] * uv31;
        float z = xz[r31 * 512 + 256 + d];
        ylast[b * 256 + d] = y * siluf(z);
    }
}

// ---------------- head ----------------
__global__ __launch_bounds__(128) void k_head(const float* __restrict__ ylast,
                                              const float* __restrict__ op_w,
                                              const float* __restrict__ fc1_w,
                                              const float* __restrict__ fc1_b,
                                              const float* __restrict__ fc2_w,
                                              const float* __restrict__ fc2_b,
                                              const float* __restrict__ q_w,
                                              const float* __restrict__ q_b,
                                              float* __restrict__ out) {
    __shared__ float s_y[256];
    __shared__ float s_l[128];
    __shared__ float s_h1[128];
    __shared__ float s_h2[128];
    const int b = blockIdx.x;
    const int j = threadIdx.x;
    s_y[j]       = ylast[b * 256 + j];
    s_y[j + 128] = ylast[b * 256 + 128 + j];
    __syncthreads();

    {
        float acc = 0.0f;
        const float* wr = op_w + (size_t)j * 256;
        for (int k = 0; k < 256; k += 4) {
            float4 wv = *(const float4*)(wr + k);
            acc += wv.x * s_y[k] + wv.y * s_y[k + 1] + wv.z * s_y[k + 2] + wv.w * s_y[k + 3];
        }
        s_l[j] = acc;
        out[1152 + b * 128 + j] = acc;
    }
    __syncthreads();
    {
        float acc = fc1_b[j];
        const float* wr = fc1_w + (size_t)j * 128;
        for (int k = 0; k < 128; k += 4) {
            float4 wv = *(const float4*)(wr + k);
            acc += wv.x * s_l[k] + wv.y * s_l[k + 1] + wv.z * s_l[k + 2] + wv.w * s_l[k + 3];
        }
        s_h1[j] = reluf(acc);
    }
    __syncthreads();
    {
        float acc = fc2_b[j];
        const float* wr = fc2_w + (size_t)j * 128;
        for (int k = 0; k < 128; k += 4) {
            float4 wv = *(const float4*)(wr + k);
            acc += wv.x * s_h1[k] + wv.y * s_h1[k + 1] + wv.z * s_h1[k + 2] + wv.w * s_h1[k + 3];
        }
        s_h2[j] = reluf(acc);
    }
    __syncthreads();
    if (j < 18) {
        float acc = q_b[j];
        const float* wr = q_w + (size_t)j * 128;
        for (int k = 0; k < 128; k += 4) {
            float4 wv = *(const float4*)(wr + k);
            acc += wv.x * s_h2[k] + wv.y * s_h2[k + 1] + wv.z * s_h2[k + 2] + wv.w * s_h2[k + 3];
        }
        out[b * 18 + j] = acc;
    }
}

// ---------------- launch ----------------
extern "C" void kernel_launch(void* const* d_in, const int* in_sizes, int n_in,
                              void* d_out, int out_size, void* d_ws, size_t ws_size,
                              hipStream_t stream) {
    const float* x        = (const float*)d_in[0];
    const float* conv1_w  = (const float*)d_in[1];
    const float* conv1_b  = (const float*)d_in[2];
    const float* conv2_w  = (const float*)d_in[3];
    const float* conv2_b  = (const float*)d_in[4];
    const float* conv3_w  = (const float*)d_in[5];
    const float* conv3_b  = (const float*)d_in[6];
    const float* feat_w   = (const float*)d_in[7];
    const float* feat_b   = (const float*)d_in[8];
    const float* in_proj_w = (const float*)d_in[9];
    const float* conv1d_w = (const float*)d_in[10];
    const float* conv1d_b = (const float*)d_in[11];
    const float* x_proj_w = (const float*)d_in[12];
    const float* dt_proj_w = (const float*)d_in[13];
    const float* dt_proj_b = (const float*)d_in[14];
    const float* A_log    = (const float*)d_in[15];
    const float* Dvec     = (const float*)d_in[16];
    const float* out_proj_w = (const float*)d_in[17];
    const float* fc1_w    = (const float*)d_in[18];
    const float* fc1_b    = (const float*)d_in[19];
    const float* fc2_w    = (const float*)d_in[20];
    const float* fc2_b    = (const float*)d_in[21];
    const float* q_w      = (const float*)d_in[22];
    const float* q_b      = (const float*)d_in[23];
    float* out = (float*)d_out;

    float* ws = (float*)d_ws;
    float* c1    = ws;                    // 2048*32*400
    float* c2    = ws + 26214400;         // 2048*64*81
    float* c3    = ws;                    // 2048*3136 (reuses c1)
    float* featP = ws + 6422528;          // 7*2048*128
    float* feat  = ws + 8257536;          // 2048*128
    float* xz    = ws + 8519680;          // 2048*512
    float* u     = ws + 9568256;          // 2048*256
    float* xdbl  = ws + 10092544;         // 2048*72
    float* dt    = ws + 10240000;         // 2048*256
    float* ylast = ws + 10764288;         // 64*256

    k_conv1<<<dim3(NIMG, 4), dim3(192), 0, stream>>>(x, conv1_w, conv1_b, c1);
    k_conv2<<<dim3(NIMG), dim3(192), 0, stream>>>(c1, conv2_w, conv2_b, c2);
    k_conv3<<<dim3(NIMG), dim3(128), 0, stream>>>(c2, conv3_w, conv3_b, c3);

    k_gemm<<<dim3(32, 2, 7), dim3(256), 0, stream>>>(c3, feat_w, featP, 2048, 128, 3136, 448);
    k_reduce7<<<dim3(1024), dim3(256), 0, stream>>>(featP, feat_b, feat);

    k_gemm<<<dim3(32, 8, 1), dim3(256), 0, stream>>>(feat, in_proj_w, xz, 2048, 512, 128, 128);
    k_conv1d<<<dim3(64, 4), dim3(256), 0, stream>>>(xz, conv1d_w, conv1d_b, u);
    k_gemm<<<dim3(32, 2, 1), dim3(256), 0, stream>>>(u, x_proj_w, xdbl, 2048, 72, 256, 256);
    k_dtproj<<<dim3(2048), dim3(256), 0, stream>>>(xdbl, dt_proj_w, dt_proj_b, dt);
    k_scan<<<dim3(2048), dim3(256), 0, stream>>>(xdbl, dt, u, A_log, Dvec, xz, ylast);
    k_head<<<dim3(64), dim3(128), 0, stream>>>(ylast, out_proj_w, fc1_w, fc1_b,
                                               fc2_w, fc2_b, q_w, q_b, out);
}

// Round 3
// 1788.993 us; speedup vs baseline: 2.6691x; 2.6691x over previous
//
#include <hip/hip_runtime.h>
#include <math.h>

// ---------------- constants ----------------
#define NIMG   2048   // B*S
#define BATCH  64
#define SEQ    32

__device__ __forceinline__ float siluf(float v) { return v / (1.0f + expf(-v)); }
__device__ __forceinline__ float reluf(float v) { return v > 0.0f ? v : 0.0f; }
__device__ __forceinline__ float softplusf(float x) {
    return x > 0.0f ? x + log1pf(expf(-x)) : log1pf(expf(x));
}

// ---------------- conv1: (2048,4,84,84)/255 -> (2048,32,20,20), k=8 s=4, relu ----
// grid (2048,4): image x 5-output-row chunk. block 192 (160 compute).
// Weights staged in LDS (stride 260 pad -> 2-way max on broadcast reads).
__global__ __launch_bounds__(192) void k_conv1(const float* __restrict__ x,
                                               const float* __restrict__ w,
                                               const float* __restrict__ bias,
                                               float* __restrict__ out) {
    __shared__ float s_in[4][24][84];     // 32.25 KB
    __shared__ float s_w[32 * 260];       // 33.28 KB  (oc stride 260: pad +4)
    const int tid = threadIdx.x;
    const int img = blockIdx.x;
    const int chunk = blockIdx.y;           // 5 output rows per chunk
    const float* __restrict__ xin = x + (size_t)img * (4 * 84 * 84);
    const int row0 = chunk * 20;            // first input row of chunk

    // stage weights: 8192 floats = 2048 float4
    for (int i = tid; i < 2048; i += 192) {
        int oc = i >> 6;            // 64 float4 per oc
        int r  = (i & 63) * 4;
        *(float4*)&s_w[oc * 260 + r] = *(const float4*)&w[(size_t)i * 4];
    }
    // stage input: 24 rows x 84 cols x 4 ic (2016 float4)
    for (int i = tid; i < 2016; i += 192) {
        int ic = i / 504, rem = i % 504;
        int r = rem / 21, c4 = rem % 21;
        float4 v = *(const float4*)&xin[(size_t)(ic * 84 + row0 + r) * 84 + c4 * 4];
        v.x *= (1.0f / 255.0f); v.y *= (1.0f / 255.0f);
        v.z *= (1.0f / 255.0f); v.w *= (1.0f / 255.0f);
        *(float4*)&s_in[ic][r][c4 * 4] = v;
    }
    __syncthreads();

    if (tid < 160) {
        const int ocg = tid / 20;           // 0..7 (4 oc each)
        const int pix = tid % 20;
        const int oy_l = pix / 4;           // 0..4
        const int oxg  = pix % 4;           // 0..3 (5 ox each)
        const int oc0 = ocg * 4;
        const int iy0 = oy_l * 4;
        const int col0 = oxg * 20;

        float acc[4][5];
        #pragma unroll
        for (int o = 0; o < 4; ++o)
            #pragma unroll
            for (int j = 0; j < 5; ++j) acc[o][j] = 0.0f;

        for (int ic = 0; ic < 4; ++ic) {
            #pragma unroll
            for (int ky = 0; ky < 8; ++ky) {
                const float* irow = &s_in[ic][iy0 + ky][col0];
                float xr[24];
                #pragma unroll
                for (int t = 0; t < 6; ++t) {
                    float4 v = *(const float4*)(irow + t * 4);
                    xr[t * 4] = v.x; xr[t * 4 + 1] = v.y; xr[t * 4 + 2] = v.z; xr[t * 4 + 3] = v.w;
                }
                #pragma unroll
                for (int o = 0; o < 4; ++o) {
                    const float* wp = &s_w[(oc0 + o) * 260 + ic * 64 + ky * 8];
                    float4 wa = *(const float4*)wp;
                    float4 wb = *(const float4*)(wp + 4);
                    #pragma unroll
                    for (int j = 0; j < 5; ++j) {
                        const float* xp = &xr[j * 4];
                        acc[o][j] += wa.x * xp[0] + wa.y * xp[1] + wa.z * xp[2] + wa.w * xp[3]
                                   + wb.x * xp[4] + wb.y * xp[5] + wb.z * xp[6] + wb.w * xp[7];
                    }
                }
            }
        }

        const int oy = chunk * 5 + oy_l;
        #pragma unroll
        for (int o = 0; o < 4; ++o) {
            float bb = bias[oc0 + o];
            #pragma unroll
            for (int j = 0; j < 5; ++j)
                out[((size_t)img * 32 + oc0 + o) * 400 + oy * 20 + oxg * 5 + j] = reluf(acc[o][j] + bb);
        }
    }
}

// ---------------- conv2: (2048,32,20,20) -> (2048,64,9,9), k=4 s=2, relu ----
// grid 2048, block 192 (144 compute). thread tile 4oc x 9ox.
__global__ __launch_bounds__(192, 2) void k_conv2(const float* __restrict__ in,
                                                  const float* __restrict__ w,
                                                  const float* __restrict__ bias,
                                                  float* __restrict__ out) {
    __shared__ float s_in[32][20][20];  // 51.2 KB
    const int tid = threadIdx.x;
    const int img = blockIdx.x;
    const float* __restrict__ src = in + (size_t)img * 12800;
    for (int i = tid; i < 3200; i += 192) ((float4*)s_in)[i] = ((const float4*)src)[i];
    __syncthreads();

    if (tid < 144) {
        const int ocg = tid / 9, oy = tid % 9;
        const int oc0 = ocg * 4;
        float acc[4][9];
        #pragma unroll
        for (int o = 0; o < 4; ++o)
            #pragma unroll
            for (int j = 0; j < 9; ++j) acc[o][j] = 0.0f;

        for (int ic = 0; ic < 32; ++ic) {
            #pragma unroll
            for (int ky = 0; ky < 4; ++ky) {
                const float* irow = &s_in[ic][2 * oy + ky][0];
                float xr[20];
                #pragma unroll
                for (int t = 0; t < 5; ++t) {
                    float4 v = *(const float4*)(irow + t * 4);
                    xr[t * 4] = v.x; xr[t * 4 + 1] = v.y; xr[t * 4 + 2] = v.z; xr[t * 4 + 3] = v.w;
                }
                #pragma unroll
                for (int o = 0; o < 4; ++o) {
                    float4 wv = *(const float4*)(w + ((size_t)(oc0 + o) * 32 + ic) * 16 + ky * 4);
                    #pragma unroll
                    for (int ox = 0; ox < 9; ++ox) {
                        acc[o][ox] += wv.x * xr[2 * ox] + wv.y * xr[2 * ox + 1]
                                    + wv.z * xr[2 * ox + 2] + wv.w * xr[2 * ox + 3];
                    }
                }
            }
        }
        #pragma unroll
        for (int o = 0; o < 4; ++o) {
            float bb = bias[oc0 + o];
            #pragma unroll
            for (int ox = 0; ox < 9; ++ox)
                out[((size_t)img * 64 + oc0 + o) * 81 + oy * 9 + ox] = reluf(acc[o][ox] + bb);
        }
    }
}

// ---------------- conv3: (2048,64,9,9) -> (2048,64,7,7) flat, k=3 s=1, relu ----
__global__ __launch_bounds__(128, 2) void k_conv3(const float* __restrict__ in,
                                                  const float* __restrict__ w,
                                                  const float* __restrict__ bias,
                                                  float* __restrict__ out) {
    __shared__ float s_in[64][9][12];   // 27.6 KB
    const int tid = threadIdx.x;
    const int img = blockIdx.x;
    const float* __restrict__ src = in + (size_t)img * 5184;
    for (int i = tid; i < 1296; i += 128) {
        float4 v = ((const float4*)src)[i];
        int base = i * 4;
        #pragma unroll
        for (int e = 0; e < 4; ++e) {
            int idx = base + e;
            int ic = idx / 81, rem = idx % 81;
            float val = (e == 0) ? v.x : (e == 1) ? v.y : (e == 2) ? v.z : v.w;
            s_in[ic][rem / 9][rem % 9] = val;
        }
    }
    __syncthreads();

    if (tid < 112) {
        const int ocg = tid / 7, oy = tid % 7;
        const int oc0 = ocg * 4;
        float acc[4][7];
        #pragma unroll
        for (int o = 0; o < 4; ++o)
            #pragma unroll
            for (int j = 0; j < 7; ++j) acc[o][j] = 0.0f;

        for (int ic = 0; ic < 64; ++ic) {
            #pragma unroll
            for (int ky = 0; ky < 3; ++ky) {
                const float* irow = &s_in[ic][oy + ky][0];
                float xr[12];
                #pragma unroll
                for (int t = 0; t < 3; ++t) {
                    float4 v = *(const float4*)(irow + t * 4);
                    xr[t * 4] = v.x; xr[t * 4 + 1] = v.y; xr[t * 4 + 2] = v.z; xr[t * 4 + 3] = v.w;
                }
                #pragma unroll
                for (int o = 0; o < 4; ++o) {
                    const float* wp = w + ((size_t)(oc0 + o) * 64 + ic) * 9 + ky * 3;
                    float w0 = wp[0], w1 = wp[1], w2 = wp[2];
                    #pragma unroll
                    for (int ox = 0; ox < 7; ++ox)
                        acc[o][ox] += w0 * xr[ox] + w1 * xr[ox + 1] + w2 * xr[ox + 2];
                }
            }
        }
        #pragma unroll
        for (int o = 0; o < 4; ++o) {
            float bb = bias[oc0 + o];
            #pragma unroll
            for (int ox = 0; ox < 7; ++ox)
                out[(size_t)img * 3136 + (oc0 + o) * 49 + oy * 7 + ox] = reluf(acc[o][ox] + bb);
        }
    }
}

// ---------------- generic fp32 GEMM: C[M,N] = A[M,K] @ W[N,K]^T ----
__global__ __launch_bounds__(256) void k_gemm(const float* __restrict__ A,
                                              const float* __restrict__ W,
                                              float* __restrict__ C,
                                              int M, int N, int K, int kpz) {
    __shared__ float As[16][68];
    __shared__ float Ws[16][68];
    const int tid = threadIdx.x;
    const int m0 = blockIdx.x * 64, n0 = blockIdx.y * 64;
    const int k0 = blockIdx.z * kpz;
    const int lr = tid >> 4, lc = tid & 15;
    const int tm = tid >> 4, tn = tid & 15;

    float acc[4][4];
    #pragma unroll
    for (int i = 0; i < 4; ++i)
        #pragma unroll
        for (int j = 0; j < 4; ++j) acc[i][j] = 0.0f;

    for (int kc = 0; kc < kpz; kc += 16) {
        const int kb = k0 + kc + lc;
        __syncthreads();
        #pragma unroll
        for (int i = 0; i < 4; ++i) {
            int r = lr + 16 * i;
            As[lc][r] = A[(size_t)(m0 + r) * K + kb];
            int wr = n0 + r;
            Ws[lc][r] = (wr < N) ? W[(size_t)wr * K + kb] : 0.0f;
        }
        __syncthreads();
        #pragma unroll
        for (int kk = 0; kk < 16; ++kk) {
            float4 a = *(const float4*)&As[kk][tm * 4];
            float4 b = *(const float4*)&Ws[kk][tn * 4];
            acc[0][0] += a.x * b.x; acc[0][1] += a.x * b.y; acc[0][2] += a.x * b.z; acc[0][3] += a.x * b.w;
            acc[1][0] += a.y * b.x; acc[1][1] += a.y * b.y; acc[1][2] += a.y * b.z; acc[1][3] += a.y * b.w;
            acc[2][0] += a.z * b.x; acc[2][1] += a.z * b.y; acc[2][2] += a.z * b.z; acc[2][3] += a.z * b.w;
            acc[3][0] += a.w * b.x; acc[3][1] += a.w * b.y; acc[3][2] += a.w * b.z; acc[3][3] += a.w * b.w;
        }
    }

    float* Cz = C + (size_t)blockIdx.z * M * N;
    #pragma unroll
    for (int i = 0; i < 4; ++i) {
        int m = m0 + tm * 4 + i;
        #pragma unroll
        for (int j = 0; j < 4; ++j) {
            int n = n0 + tn * 4 + j;
            if (n < N) Cz[(size_t)m * N + n] = acc[i][j];
        }
    }
}

// ---------------- reduce 7 K-split partials + bias ----
__global__ __launch_bounds__(256) void k_reduce7(const float* __restrict__ P,
                                                 const float* __restrict__ bias,
                                                 float* __restrict__ out) {
    int idx = blockIdx.x * 256 + threadIdx.x;
    int n = idx & 127;
    float s = bias[n];
    #pragma unroll
    for (int z = 0; z < 7; ++z) s += P[(size_t)z * 2048 * 128 + idx];
    out[idx] = s;
}

// ---------------- depthwise causal conv1d (k=4) + bias + silu ----
__global__ __launch_bounds__(256) void k_conv1d(const float* __restrict__ xz,
                                                const float* __restrict__ w,
                                                const float* __restrict__ bias,
                                                float* __restrict__ u) {
    const int b = blockIdx.x, sg = blockIdx.y;
    const int d = threadIdx.x;
    const float w0 = w[d * 4], w1 = w[d * 4 + 1], w2 = w[d * 4 + 2], w3 = w[d * 4 + 3];
    const float bb = bias[d];
    const int s0 = sg * 8;
    float p1 = 0.0f, p2 = 0.0f, p3 = 0.0f;
    int sstart = (sg == 0) ? 0 : s0 - 3;
    for (int s = sstart; s < s0 + 8; ++s) {
        float cur = xz[(size_t)(b * 32 + s) * 512 + d];
        if (s >= s0) {
            float v = w0 * p3 + w1 * p2 + w2 * p1 + w3 * cur + bb;
            u[(size_t)(b * 32 + s) * 256 + d] = siluf(v);
        }
        p3 = p2; p2 = p1; p1 = cur;
    }
}

// ---------------- dt = softplus(x_dbl[:, :8] @ dt_proj_w^T + dt_proj_b) ----
__global__ __launch_bounds__(256) void k_dtproj(const float* __restrict__ xdbl,
                                                const float* __restrict__ w,
                                                const float* __restrict__ bias,
                                                float* __restrict__ dt) {
    const int row = blockIdx.x;
    const int j = threadIdx.x;
    float r[8];
    #pragma unroll
    for (int k = 0; k < 8; ++k) r[k] = xdbl[(size_t)row * 72 + k];
    float acc = bias[j];
    #pragma unroll
    for (int k = 0; k < 8; ++k) acc += r[k] * w[j * 8 + k];
    dt[(size_t)row * 256 + j] = softplusf(acc);
}

// ---------------- selective scan; only final-timestep output needed ----
__global__ __launch_bounds__(256) void k_scan(const float* __restrict__ xdbl,
                                              const float* __restrict__ dt,
                                              const float* __restrict__ u,
                                              const float* __restrict__ A_log,
                                              const float* __restrict__ Dv,
                                              const float* __restrict__ xz,
                                              float* __restrict__ ylast) {
    const int blk = blockIdx.x;
    const int b = blk >> 5, dg = blk & 31;
    const int lane = threadIdx.x & 63;
    const int wv = threadIdx.x >> 6;
    const int n = lane & 31;
    const int d = dg * 8 + wv * 2 + (lane >> 5);

    const float A = -expf(A_log[d * 32 + n]);
    float h = 0.0f;
    const size_t rowbase = (size_t)b * 32;
    for (int s = 0; s < 32; ++s) {
        size_t r = rowbase + s;
        float dtv = dt[r * 256 + d];
        float Bn  = xdbl[r * 72 + 8 + n];
        float uv  = u[r * 256 + d];
        float dA  = expf(dtv * A);
        h = dA * h + dtv * Bn * uv;
    }
    size_t r31 = rowbase + 31;
    float yv = h * xdbl[r31 * 72 + 40 + n];
    #pragma unroll
    for (int off = 16; off > 0; off >>= 1) yv += __shfl_xor(yv, off);
    if (n == 0) {
        float uv31 = u[r31 * 256 + d];
        float y = yv + Dv[d] * uv31;
        float z = xz[r31 * 512 + 256 + d];
        ylast[b * 256 + d] = y * siluf(z);
    }
}

// ---------------- head ----------------
__global__ __launch_bounds__(128) void k_head(const float* __restrict__ ylast,
                                              const float* __restrict__ op_w,
                                              const float* __restrict__ fc1_w,
                                              const float* __restrict__ fc1_b,
                                              const float* __restrict__ fc2_w,
                                              const float* __restrict__ fc2_b,
                                              const float* __restrict__ q_w,
                                              const float* __restrict__ q_b,
                                              float* __restrict__ out) {
    __shared__ float s_y[256];
    __shared__ float s_l[128];
    __shared__ float s_h1[128];
    __shared__ float s_h2[128];
    const int b = blockIdx.x;
    const int j = threadIdx.x;
    s_y[j]       = ylast[b * 256 + j];
    s_y[j + 128] = ylast[b * 256 + 128 + j];
    __syncthreads();

    {
        float acc = 0.0f;
        const float* wr = op_w + (size_t)j * 256;
        for (int k = 0; k < 256; k += 4) {
            float4 wv = *(const float4*)(wr + k);
            acc += wv.x * s_y[k] + wv.y * s_y[k + 1] + wv.z * s_y[k + 2] + wv.w * s_y[k + 3];
        }
        s_l[j] = acc;
        out[1152 + b * 128 + j] = acc;
    }
    __syncthreads();
    {
        float acc = fc1_b[j];
        const float* wr = fc1_w + (size_t)j * 128;
        for (int k = 0; k < 128; k += 4) {
            float4 wv = *(const float4*)(wr + k);
            acc += wv.x * s_l[k] + wv.y * s_l[k + 1] + wv.z * s_l[k + 2] + wv.w * s_l[k + 3];
        }
        s_h1[j] = reluf(acc);
    }
    __syncthreads();
    {
        float acc = fc2_b[j];
        const float* wr = fc2_w + (size_t)j * 128;
        for (int k = 0; k < 128; k += 4) {
            float4 wv = *(const float4*)(wr + k);
            acc += wv.x * s_h1[k] + wv.y * s_h1[k + 1] + wv.z * s_h1[k + 2] + wv.w * s_h1[k + 3];
        }
        s_h2[j] = reluf(acc);
    }
    __syncthreads();
    if (j < 18) {
        float acc = q_b[j];
        const float* wr = q_w + (size_t)j * 128;
        for (int k = 0; k < 128; k += 4) {
            float4 wv = *(const float4*)(wr + k);
            acc += wv.x * s_h2[k] + wv.y * s_h2[k + 1] + wv.z * s_h2[k + 2] + wv.w * s_h2[k + 3];
        }
        out[b * 18 + j] = acc;
    }
}

// ---------------- launch ----------------
extern "C" void kernel_launch(void* const* d_in, const int* in_sizes, int n_in,
                              void* d_out, int out_size, void* d_ws, size_t ws_size,
                              hipStream_t stream) {
    const float* x        = (const float*)d_in[0];
    const float* conv1_w  = (const float*)d_in[1];
    const float* conv1_b  = (const float*)d_in[2];
    const float* conv2_w  = (const float*)d_in[3];
    const float* conv2_b  = (const float*)d_in[4];
    const float* conv3_w  = (const float*)d_in[5];
    const float* conv3_b  = (const float*)d_in[6];
    const float* feat_w   = (const float*)d_in[7];
    const float* feat_b   = (const float*)d_in[8];
    const float* in_proj_w = (const float*)d_in[9];
    const float* conv1d_w = (const float*)d_in[10];
    const float* conv1d_b = (const float*)d_in[11];
    const float* x_proj_w = (const float*)d_in[12];
    const float* dt_proj_w = (const float*)d_in[13];
    const float* dt_proj_b = (const float*)d_in[14];
    const float* A_log    = (const float*)d_in[15];
    const float* Dvec     = (const float*)d_in[16];
    const float* out_proj_w = (const float*)d_in[17];
    const float* fc1_w    = (const float*)d_in[18];
    const float* fc1_b    = (const float*)d_in[19];
    const float* fc2_w    = (const float*)d_in[20];
    const float* fc2_b    = (const float*)d_in[21];
    const float* q_w      = (const float*)d_in[22];
    const float* q_b      = (const float*)d_in[23];
    float* out = (float*)d_out;

    float* ws = (float*)d_ws;
    float* c1    = ws;                    // 2048*32*400
    float* c2    = ws + 26214400;         // 2048*64*81
    float* c3    = ws;                    // 2048*3136 (reuses c1)
    float* featP = ws + 6422528;          // 7*2048*128
    float* feat  = ws + 8257536;          // 2048*128
    float* xz    = ws + 8519680;          // 2048*512
    float* u     = ws + 9568256;          // 2048*256
    float* xdbl  = ws + 10092544;         // 2048*72
    float* dt    = ws + 10240000;         // 2048*256
    float* ylast = ws + 10764288;         // 64*256

    k_conv1<<<dim3(NIMG, 4), dim3(192), 0, stream>>>(x, conv1_w, conv1_b, c1);
    k_conv2<<<dim3(NIMG), dim3(192), 0, stream>>>(c1, conv2_w, conv2_b, c2);
    k_conv3<<<dim3(NIMG), dim3(128), 0, stream>>>(c2, conv3_w, conv3_b, c3);

    k_gemm<<<dim3(32, 2, 7), dim3(256), 0, stream>>>(c3, feat_w, featP, 2048, 128, 3136, 448);
    k_reduce7<<<dim3(1024), dim3(256), 0, stream>>>(featP, feat_b, feat);

    k_gemm<<<dim3(32, 8, 1), dim3(256), 0, stream>>>(feat, in_proj_w, xz, 2048, 512, 128, 128);
    k_conv1d<<<dim3(64, 4), dim3(256), 0, stream>>>(xz, conv1d_w, conv1d_b, u);
    k_gemm<<<dim3(32, 2, 1), dim3(256), 0, stream>>>(u, x_proj_w, xdbl, 2048, 72, 256, 256);
    k_dtproj<<<dim3(2048), dim3(256), 0, stream>>>(xdbl, dt_proj_w, dt_proj_b, dt);
    k_scan<<<dim3(2048), dim3(256), 0, stream>>>(xdbl, dt, u, A_log, Dvec, xz, ylast);
    k_head<<<dim3(64), dim3(128), 0, stream>>>(ylast, out_proj_w, fc1_w, fc1_b,
                                               fc2_w, fc2_b, q_w, q_b, out);
}

// Round 5
// 1256.964 us; speedup vs baseline: 3.7989x; 1.4233x over previous
//
#include <hip/hip_runtime.h>
#include <math.h>

// ---------------- constants ----------------
#define NIMG   2048   // B*S
#define BATCH  64
#define SEQ    32

typedef __attribute__((ext_vector_type(8))) short short8;
typedef __attribute__((ext_vector_type(4))) float f32x4;

__device__ __forceinline__ float siluf(float v) { return v / (1.0f + expf(-v)); }
__device__ __forceinline__ float reluf(float v) { return v > 0.0f ? v : 0.0f; }
__device__ __forceinline__ float softplusf(float x) {
    return x > 0.0f ? x + log1pf(expf(-x)) : log1pf(expf(x));
}

// round-to-nearest-even fp32 -> bf16 (upper 16 bits)
__device__ __forceinline__ unsigned bf16_rne_bits(float f) {
    unsigned u = __float_as_uint(f);
    return (u + 0x7FFFu + ((u >> 16) & 1u)) & 0xFFFF0000u;   // bf16 bits in high half
}

// ---------------- conv1 via MFMA implicit GEMM ----------------
// per image: C[400 pix][32 oc] = A[400][256] * W[256][32], 3-term bf16 split.
// grid 2048 (image), block 256 (4 waves). W staged LDS->regs; A from global.
__global__ __launch_bounds__(256) void k_conv1(const float* __restrict__ x,
                                               const float* __restrict__ w,
                                               const float* __restrict__ bias,
                                               float* __restrict__ out) {
    __shared__ short s_w[2][8][2][64][8];   // [term][kstep][octile][lane][j] = 32 KB
    const int tid = threadIdx.x;
    const int img = blockIdx.x;
    const float* __restrict__ xin = x + (size_t)img * (4 * 84 * 84);

    // ---- stage weights (w * 1/255), hi/lo split, MFMA fragment layout ----
    for (int idx = tid; idx < 8192; idx += 256) {
        int j = idx & 7, ln = (idx >> 3) & 63, o = (idx >> 9) & 1, t = idx >> 10;
        int k  = t * 32 + (ln >> 4) * 8 + j;        // k = ic*64 + ky*8 + kx
        int oc = o * 16 + (ln & 15);
        float v = w[oc * 256 + k] * (1.0f / 255.0f);
        unsigned uh = bf16_rne_bits(v);
        float hf = __uint_as_float(uh);
        unsigned ul = bf16_rne_bits(v - hf);
        s_w[0][t][o][ln][j] = (short)(uh >> 16);
        s_w[1][t][o][ln][j] = (short)(ul >> 16);
    }
    __syncthreads();

    const int lane = tid & 63;
    const int wv   = tid >> 6;
    const int prow = lane & 15;     // A-row (pixel) / C-col (oc)
    const int kg   = lane >> 4;     // k-group of 8

    // hoist all W fragments into registers: 32 x short8 = 128 VGPR
    short8 wh[8][2], wl[8][2];
    #pragma unroll
    for (int t = 0; t < 8; ++t) {
        #pragma unroll
        for (int o = 0; o < 2; ++o) {
            wh[t][o] = *(const short8*)&s_w[0][t][o][lane][0];
            wl[t][o] = *(const short8*)&s_w[1][t][o][lane][0];
        }
    }

    for (int ptile = wv; ptile < 25; ptile += 4) {
        f32x4 acc0 = {0.f, 0.f, 0.f, 0.f};
        f32x4 acc1 = {0.f, 0.f, 0.f, 0.f};
        const int p  = ptile * 16 + prow;
        const int oy = p / 20, ox = p % 20;

        #pragma unroll
        for (int t = 0; t < 8; ++t) {
            const int tk = t * 4 + kg;
            const int ic = tk >> 3;
            const int ky = tk & 7;
            const float* src = xin + (size_t)(ic * 84 + oy * 4 + ky) * 84 + ox * 4;
            float a0 = src[0], a1 = src[1], a2 = src[2], a3 = src[3];
            float a4 = src[4], a5 = src[5], a6 = src[6], a7 = src[7];

            unsigned uh0 = bf16_rne_bits(a0), uh1 = bf16_rne_bits(a1);
            unsigned uh2 = bf16_rne_bits(a2), uh3 = bf16_rne_bits(a3);
            unsigned uh4 = bf16_rne_bits(a4), uh5 = bf16_rne_bits(a5);
            unsigned uh6 = bf16_rne_bits(a6), uh7 = bf16_rne_bits(a7);
            unsigned ul0 = bf16_rne_bits(a0 - __uint_as_float(uh0));
            unsigned ul1 = bf16_rne_bits(a1 - __uint_as_float(uh1));
            unsigned ul2 = bf16_rne_bits(a2 - __uint_as_float(uh2));
            unsigned ul3 = bf16_rne_bits(a3 - __uint_as_float(uh3));
            unsigned ul4 = bf16_rne_bits(a4 - __uint_as_float(uh4));
            unsigned ul5 = bf16_rne_bits(a5 - __uint_as_float(uh5));
            unsigned ul6 = bf16_rne_bits(a6 - __uint_as_float(uh6));
            unsigned ul7 = bf16_rne_bits(a7 - __uint_as_float(uh7));

            union { short8 v; unsigned u[4]; } ah, al;
            ah.u[0] = (uh0 >> 16) | (uh1 & 0xFFFF0000u);
            ah.u[1] = (uh2 >> 16) | (uh3 & 0xFFFF0000u);
            ah.u[2] = (uh4 >> 16) | (uh5 & 0xFFFF0000u);
            ah.u[3] = (uh6 >> 16) | (uh7 & 0xFFFF0000u);
            al.u[0] = (ul0 >> 16) | (ul1 & 0xFFFF0000u);
            al.u[1] = (ul2 >> 16) | (ul3 & 0xFFFF0000u);
            al.u[2] = (ul4 >> 16) | (ul5 & 0xFFFF0000u);
            al.u[3] = (ul6 >> 16) | (ul7 & 0xFFFF0000u);

            acc0 = __builtin_amdgcn_mfma_f32_16x16x32_bf16(ah.v, wh[t][0], acc0, 0, 0, 0);
            acc0 = __builtin_amdgcn_mfma_f32_16x16x32_bf16(al.v, wh[t][0], acc0, 0, 0, 0);
            acc0 = __builtin_amdgcn_mfma_f32_16x16x32_bf16(ah.v, wl[t][0], acc0, 0, 0, 0);
            acc1 = __builtin_amdgcn_mfma_f32_16x16x32_bf16(ah.v, wh[t][1], acc1, 0, 0, 0);
            acc1 = __builtin_amdgcn_mfma_f32_16x16x32_bf16(al.v, wh[t][1], acc1, 0, 0, 0);
            acc1 = __builtin_amdgcn_mfma_f32_16x16x32_bf16(ah.v, wl[t][1], acc1, 0, 0, 0);
        }

        // epilogue: C/D layout col=lane&15 (oc), row=(lane>>4)*4+reg (pixel)
        const int pix0 = ptile * 16 + kg * 4;
        {
            const int oc = prow;
            const float bb = bias[oc];
            float4 st;
            st.x = reluf(acc0.x + bb); st.y = reluf(acc0.y + bb);
            st.z = reluf(acc0.z + bb); st.w = reluf(acc0.w + bb);
            *(float4*)&out[((size_t)img * 32 + oc) * 400 + pix0] = st;
        }
        {
            const int oc = 16 + prow;
            const float bb = bias[oc];
            float4 st;
            st.x = reluf(acc1.x + bb); st.y = reluf(acc1.y + bb);
            st.z = reluf(acc1.z + bb); st.w = reluf(acc1.w + bb);
            *(float4*)&out[((size_t)img * 32 + oc) * 400 + pix0] = st;
        }
    }
}

// ---------------- conv2: (2048,32,20,20) -> (2048,64,9,9), k=4 s=2, relu ----
// grid 2048, block 192 (144 compute). thread tile 4oc x 9ox.
__global__ __launch_bounds__(192, 2) void k_conv2(const float* __restrict__ in,
                                                  const float* __restrict__ w,
                                                  const float* __restrict__ bias,
                                                  float* __restrict__ out) {
    __shared__ float s_in[32][20][20];  // 51.2 KB
    const int tid = threadIdx.x;
    const int img = blockIdx.x;
    const float* __restrict__ src = in + (size_t)img * 12800;
    for (int i = tid; i < 3200; i += 192) ((float4*)s_in)[i] = ((const float4*)src)[i];
    __syncthreads();

    if (tid < 144) {
        const int ocg = tid / 9, oy = tid % 9;
        const int oc0 = ocg * 4;
        float acc[4][9];
        #pragma unroll
        for (int o = 0; o < 4; ++o)
            #pragma unroll
            for (int j = 0; j < 9; ++j) acc[o][j] = 0.0f;

        for (int ic = 0; ic < 32; ++ic) {
            #pragma unroll
            for (int ky = 0; ky < 4; ++ky) {
                const float* irow = &s_in[ic][2 * oy + ky][0];
                float xr[20];
                #pragma unroll
                for (int t = 0; t < 5; ++t) {
                    float4 v = *(const float4*)(irow + t * 4);
                    xr[t * 4] = v.x; xr[t * 4 + 1] = v.y; xr[t * 4 + 2] = v.z; xr[t * 4 + 3] = v.w;
                }
                #pragma unroll
                for (int o = 0; o < 4; ++o) {
                    float4 wv = *(const float4*)(w + ((size_t)(oc0 + o) * 32 + ic) * 16 + ky * 4);
                    #pragma unroll
                    for (int ox = 0; ox < 9; ++ox) {
                        acc[o][ox] += wv.x * xr[2 * ox] + wv.y * xr[2 * ox + 1]
                                    + wv.z * xr[2 * ox + 2] + wv.w * xr[2 * ox + 3];
                    }
                }
            }
        }
        #pragma unroll
        for (int o = 0; o < 4; ++o) {
            float bb = bias[oc0 + o];
            #pragma unroll
            for (int ox = 0; ox < 9; ++ox)
                out[((size_t)img * 64 + oc0 + o) * 81 + oy * 9 + ox] = reluf(acc[o][ox] + bb);
        }
    }
}

// ---------------- conv3: (2048,64,9,9) -> (2048,64,7,7) flat, k=3 s=1, relu ----
__global__ __launch_bounds__(128, 2) void k_conv3(const float* __restrict__ in,
                                                  const float* __restrict__ w,
                                                  const float* __restrict__ bias,
                                                  float* __restrict__ out) {
    __shared__ float s_in[64][9][12];   // 27.6 KB
    const int tid = threadIdx.x;
    const int img = blockIdx.x;
    const float* __restrict__ src = in + (size_t)img * 5184;
    for (int i = tid; i < 1296; i += 128) {
        float4 v = ((const float4*)src)[i];
        int base = i * 4;
        #pragma unroll
        for (int e = 0; e < 4; ++e) {
            int idx = base + e;
            int ic = idx / 81, rem = idx % 81;
            float val = (e == 0) ? v.x : (e == 1) ? v.y : (e == 2) ? v.z : v.w;
            s_in[ic][rem / 9][rem % 9] = val;
        }
    }
    __syncthreads();

    if (tid < 112) {
        const int ocg = tid / 7, oy = tid % 7;
        const int oc0 = ocg * 4;
        float acc[4][7];
        #pragma unroll
        for (int o = 0; o < 4; ++o)
            #pragma unroll
            for (int j = 0; j < 7; ++j) acc[o][j] = 0.0f;

        for (int ic = 0; ic < 64; ++ic) {
            #pragma unroll
            for (int ky = 0; ky < 3; ++ky) {
                const float* irow = &s_in[ic][oy + ky][0];
                float xr[12];
                #pragma unroll
                for (int t = 0; t < 3; ++t) {
                    float4 v = *(const float4*)(irow + t * 4);
                    xr[t * 4] = v.x; xr[t * 4 + 1] = v.y; xr[t * 4 + 2] = v.z; xr[t * 4 + 3] = v.w;
                }
                #pragma unroll
                for (int o = 0; o < 4; ++o) {
                    const float* wp = w + ((size_t)(oc0 + o) * 64 + ic) * 9 + ky * 3;
                    float w0 = wp[0], w1 = wp[1], w2 = wp[2];
                    #pragma unroll
                    for (int ox = 0; ox < 7; ++ox)
                        acc[o][ox] += w0 * xr[ox] + w1 * xr[ox + 1] + w2 * xr[ox + 2];
                }
            }
        }
        #pragma unroll
        for (int o = 0; o < 4; ++o) {
            float bb = bias[oc0 + o];
            #pragma unroll
            for (int ox = 0; ox < 7; ++ox)
                out[(size_t)img * 3136 + (oc0 + o) * 49 + oy * 7 + ox] = reluf(acc[o][ox] + bb);
        }
    }
}

// ---------------- generic fp32 GEMM: C[M,N] = A[M,K] @ W[N,K]^T ----
__global__ __launch_bounds__(256) void k_gemm(const float* __restrict__ A,
                                              const float* __restrict__ W,
                                              float* __restrict__ C,
                                              int M, int N, int K, int kpz) {
    __shared__ float As[16][68];
    __shared__ float Ws[16][68];
    const int tid = threadIdx.x;
    const int m0 = blockIdx.x * 64, n0 = blockIdx.y * 64;
    const int k0 = blockIdx.z * kpz;
    const int lr = tid >> 4, lc = tid & 15;
    const int tm = tid >> 4, tn = tid & 15;

    float acc[4][4];
    #pragma unroll
    for (int i = 0; i < 4; ++i)
        #pragma unroll
        for (int j = 0; j < 4; ++j) acc[i][j] = 0.0f;

    for (int kc = 0; kc < kpz; kc += 16) {
        const int kb = k0 + kc + lc;
        __syncthreads();
        #pragma unroll
        for (int i = 0; i < 4; ++i) {
            int r = lr + 16 * i;
            As[lc][r] = A[(size_t)(m0 + r) * K + kb];
            int wr = n0 + r;
            Ws[lc][r] = (wr < N) ? W[(size_t)wr * K + kb] : 0.0f;
        }
        __syncthreads();
        #pragma unroll
        for (int kk = 0; kk < 16; ++kk) {
            float4 a = *(const float4*)&As[kk][tm * 4];
            float4 b = *(const float4*)&Ws[kk][tn * 4];
            acc[0][0] += a.x * b.x; acc[0][1] += a.x * b.y; acc[0][2] += a.x * b.z; acc[0][3] += a.x * b.w;
            acc[1][0] += a.y * b.x; acc[1][1] += a.y * b.y; acc[1][2] += a.y * b.z; acc[1][3] += a.y * b.w;
            acc[2][0] += a.z * b.x; acc[2][1] += a.z * b.y; acc[2][2] += a.z * b.z; acc[2][3] += a.z * b.w;
            acc[3][0] += a.w * b.x; acc[3][1] += a.w * b.y; acc[3][2] += a.w * b.z; acc[3][3] += a.w * b.w;
        }
    }

    float* Cz = C + (size_t)blockIdx.z * M * N;
    #pragma unroll
    for (int i = 0; i < 4; ++i) {
        int m = m0 + tm * 4 + i;
        #pragma unroll
        for (int j = 0; j < 4; ++j) {
            int n = n0 + tn * 4 + j;
            if (n < N) Cz[(size_t)m * N + n] = acc[i][j];
        }
    }
}

// ---------------- reduce 7 K-split partials + bias ----
__global__ __launch_bounds__(256) void k_reduce7(const float* __restrict__ P,
                                                 const float* __restrict__ bias,
                                                 float* __restrict__ out) {
    int idx = blockIdx.x * 256 + threadIdx.x;
    int n = idx & 127;
    float s = bias[n];
    #pragma unroll
    for (int z = 0; z < 7; ++z) s += P[(size_t)z * 2048 * 128 + idx];
    out[idx] = s;
}

// ---------------- depthwise causal conv1d (k=4) + bias + silu ----
__global__ __launch_bounds__(256) void k_conv1d(const float* __restrict__ xz,
                                                const float* __restrict__ w,
                                                const float* __restrict__ bias,
                                                float* __restrict__ u) {
    const int b = blockIdx.x, sg = blockIdx.y;
    const int d = threadIdx.x;
    const float w0 = w[d * 4], w1 = w[d * 4 + 1], w2 = w[d * 4 + 2], w3 = w[d * 4 + 3];
    const float bb = bias[d];
    const int s0 = sg * 8;
    float p1 = 0.0f, p2 = 0.0f, p3 = 0.0f;
    int sstart = (sg == 0) ? 0 : s0 - 3;
    for (int s = sstart; s < s0 + 8; ++s) {
        float cur = xz[(size_t)(b * 32 + s) * 512 + d];
        if (s >= s0) {
            float v = w0 * p3 + w1 * p2 + w2 * p1 + w3 * cur + bb;
            u[(size_t)(b * 32 + s) * 256 + d] = siluf(v);
        }
        p3 = p2; p2 = p1; p1 = cur;
    }
}

// ---------------- dt = softplus(x_dbl[:, :8] @ dt_proj_w^T + dt_proj_b) ----
__global__ __launch_bounds__(256) void k_dtproj(const float* __restrict__ xdbl,
                                                const float* __restrict__ w,
                                                const float* __restrict__ bias,
                                                float* __restrict__ dt) {
    const int row = blockIdx.x;
    const int j = threadIdx.x;
    float r[8];
    #pragma unroll
    for (int k = 0; k < 8; ++k) r[k] = xdbl[(size_t)row * 72 + k];
    float acc = bias[j];
    #pragma unroll
    for (int k = 0; k < 8; ++k) acc += r[k] * w[j * 8 + k];
    dt[(size_t)row * 256 + j] = softplusf(acc);
}

// ---------------- selective scan; only final-timestep output needed ----
__global__ __launch_bounds__(256) void k_scan(const float* __restrict__ xdbl,
                                              const float* __restrict__ dt,
                                              const float* __restrict__ u,
                                              const float* __restrict__ A_log,
                                              const float* __restrict__ Dv,
                                              const float* __restrict__ xz,
                                              float* __restrict__ ylast) {
    const int blk = blockIdx.x;
    const int b = blk >> 5, dg = blk & 31;
    const int lane = threadIdx.x & 63;
    const int wv = threadIdx.x >> 6;
    const int n = lane & 31;
    const int d = dg * 8 + wv * 2 + (lane >> 5);

    const float A = -expf(A_log[d * 32 + n]);
    float h = 0.0f;
    const size_t rowbase = (size_t)b * 32;
    for (int s = 0; s < 32; ++s) {
        size_t r = rowbase + s;
        float dtv = dt[r * 256 + d];
        float Bn  = xdbl[r * 72 + 8 + n];
        float uv  = u[r * 256 + d];
        float dA  = expf(dtv * A);
        h = dA * h + dtv * Bn * uv;
    }
    size_t r31 = rowbase + 31;
    float yv = h * xdbl[r31 * 72 + 40 + n];
    #pragma unroll
    for (int off = 16; off > 0; off >>= 1) yv += __shfl_xor(yv, off);
    if (n == 0) {
        float uv31 = u[r31 * 256 + d];
        float y = yv + Dv[d] * uv31;
        float z = xz[r31 * 512 + 256 + d];
        ylast[b * 256 + d] = y * siluf(z);
    }
}

// ---------------- head ----------------
__global__ __launch_bounds__(128) void k_head(const float* __restrict__ ylast,
                                              const float* __restrict__ op_w,
                                              const float* __restrict__ fc1_w,
                                              const float* __restrict__ fc1_b,
                                              const float* __restrict__ fc2_w,
                                              const float* __restrict__ fc2_b,
                                              const float* __restrict__ q_w,
                                              const float* __restrict__ q_b,
                                              float* __restrict__ out) {
    __shared__ float s_y[256];
    __shared__ float s_l[128];
    __shared__ float s_h1[128];
    __shared__ float s_h2[128];
    const int b = blockIdx.x;
    const int j = threadIdx.x;
    s_y[j]       = ylast[b * 256 + j];
    s_y[j + 128] = ylast[b * 256 + 128 + j];
    __syncthreads();

    {
        float acc = 0.0f;
        const float* wr = op_w + (size_t)j * 256;
        for (int k = 0; k < 256; k += 4) {
            float4 wv = *(const float4*)(wr + k);
            acc += wv.x * s_y[k] + wv.y * s_y[k + 1] + wv.z * s_y[k + 2] + wv.w * s_y[k + 3];
        }
        s_l[j] = acc;
        out[1152 + b * 128 + j] = acc;
    }
    __syncthreads();
    {
        float acc = fc1_b[j];
        const float* wr = fc1_w + (size_t)j * 128;
        for (int k = 0; k < 128; k += 4) {
            float4 wv = *(const float4*)(wr + k);
            acc += wv.x * s_l[k] + wv.y * s_l[k + 1] + wv.z * s_l[k + 2] + wv.w * s_l[k + 3];
        }
        s_h1[j] = reluf(acc);
    }
    __syncthreads();
    {
        float acc = fc2_b[j];
        const float* wr = fc2_w + (size_t)j * 128;
        for (int k = 0; k < 128; k += 4) {
            float4 wv = *(const float4*)(wr + k);
            acc += wv.x * s_h1[k] + wv.y * s_h1[k + 1] + wv.z * s_h1[k + 2] + wv.w * s_h1[k + 3];
        }
        s_h2[j] = reluf(acc);
    }
    __syncthreads();
    if (j < 18) {
        float acc = q_b[j];
        const float* wr = q_w + (size_t)j * 128;
        for (int k = 0; k < 128; k += 4) {
            float4 wv = *(const float4*)(wr + k);
            acc += wv.x * s_h2[k] + wv.y * s_h2[k + 1] + wv.z * s_h2[k + 2] + wv.w * s_h2[k + 3];
        }
        out[b * 18 + j] = acc;
    }
}

// ---------------- launch ----------------
extern "C" void kernel_launch(void* const* d_in, const int* in_sizes, int n_in,
                              void* d_out, int out_size, void* d_ws, size_t ws_size,
                              hipStream_t stream) {
    const float* x        = (const float*)d_in[0];
    const float* conv1_w  = (const float*)d_in[1];
    const float* conv1_b  = (const float*)d_in[2];
    const float* conv2_w  = (const float*)d_in[3];
    const float* conv2_b  = (const float*)d_in[4];
    const float* conv3_w  = (const float*)d_in[5];
    const float* conv3_b  = (const float*)d_in[6];
    const float* feat_w   = (const float*)d_in[7];
    const float* feat_b   = (const float*)d_in[8];
    const float* in_proj_w = (const float*)d_in[9];
    const float* conv1d_w = (const float*)d_in[10];
    const float* conv1d_b = (const float*)d_in[11];
    const float* x_proj_w = (const float*)d_in[12];
    const float* dt_proj_w = (const float*)d_in[13];
    const float* dt_proj_b = (const float*)d_in[14];
    const float* A_log    = (const float*)d_in[15];
    const float* Dvec     = (const float*)d_in[16];
    const float* out_proj_w = (const float*)d_in[17];
    const float* fc1_w    = (const float*)d_in[18];
    const float* fc1_b    = (const float*)d_in[19];
    const float* fc2_w    = (const float*)d_in[20];
    const float* fc2_b    = (const float*)d_in[21];
    const float* q_w      = (const float*)d_in[22];
    const float* q_b      = (const float*)d_in[23];
    float* out = (float*)d_out;

    float* ws = (float*)d_ws;
    float* c1    = ws;                    // 2048*32*400
    float* c2    = ws + 26214400;         // 2048*64*81
    float* c3    = ws;                    // 2048*3136 (reuses c1)
    float* featP = ws + 6422528;          // 7*2048*128
    float* feat  = ws + 8257536;          // 2048*128
    float* xz    = ws + 8519680;          // 2048*512
    float* u     = ws + 9568256;          // 2048*256
    float* xdbl  = ws + 10092544;         // 2048*72
    float* dt    = ws + 10240000;         // 2048*256
    float* ylast = ws + 10764288;         // 64*256

    k_conv1<<<dim3(NIMG), dim3(256), 0, stream>>>(x, conv1_w, conv1_b, c1);
    k_conv2<<<dim3(NIMG), dim3(192), 0, stream>>>(c1, conv2_w, conv2_b, c2);
    k_conv3<<<dim3(NIMG), dim3(128), 0, stream>>>(c2, conv3_w, conv3_b, c3);

    k_gemm<<<dim3(32, 2, 7), dim3(256), 0, stream>>>(c3, feat_w, featP, 2048, 128, 3136, 448);
    k_reduce7<<<dim3(1024), dim3(256), 0, stream>>>(featP, feat_b, feat);

    k_gemm<<<dim3(32, 8, 1), dim3(256), 0, stream>>>(feat, in_proj_w, xz, 2048, 512, 128, 128);
    k_conv1d<<<dim3(64, 4), dim3(256), 0, stream>>>(xz, conv1d_w, conv1d_b, u);
    k_gemm<<<dim3(32, 2, 1), dim3(256), 0, stream>>>(u, x_proj_w, xdbl, 2048, 72, 256, 256);
    k_dtproj<<<dim3(2048), dim3(256), 0, stream>>>(xdbl, dt_proj_w, dt_proj_b, dt);
    k_scan<<<dim3(2048), dim3(256), 0, stream>>>(xdbl, dt, u, A_log, Dvec, xz, ylast);
    k_head<<<dim3(64), dim3(128), 0, stream>>>(ylast, out_proj_w, fc1_w, fc1_b,
                                               fc2_w, fc2_b, q_w, q_b, out);
}